// Round 1
// baseline (1032.300 us; speedup 1.0000x reference)
//
#include <hip/hip_runtime.h>

// Conv graph kernel: out = (norm * (x + segment_sum(x[sources], targets))) @ W
// N = 100000 nodes, E = 4000000 edges, C = 64 channels, all fp32.

constexpr int C = 64;

// --- Phase 1: edge scatter ---------------------------------------------------
// One lane per (edge, channel). Wave (64 lanes) covers exactly one edge's 64
// channels: the x[src] row read is one coalesced 256B transaction; the
// atomicAdd targets 64 consecutive floats of agg[tgt].
__global__ __launch_bounds__(256) void scatter_kernel(
    const float* __restrict__ x, const int* __restrict__ src,
    const int* __restrict__ tgt, float* __restrict__ agg, int E) {
  long long t = (long long)blockIdx.x * blockDim.x + threadIdx.x;
  int e = (int)(t >> 6);
  int c = (int)(t & 63);
  if (e < E) {
    int s = src[e];   // broadcast within wave (all lanes same address)
    int d = tgt[e];
    float v = x[(long long)s * C + c];
    atomicAdd(&agg[(long long)d * C + c], v);
  }
}

// --- Phase 2: scale + 64x64 matmul ------------------------------------------
// One wave per node per iteration. Lane j holds output column j.
// h_k broadcast via __shfl over the 64-lane wave; W staged in LDS.
// LDS w[k][lane]: addr = k*64+lane -> bank = lane%32 -> 2-way aliasing (free).
constexpr int NODES_PER_BLOCK = 32;  // 4 waves x 8 nodes each

__global__ __launch_bounds__(256) void matmul_kernel(
    const float* __restrict__ x, const float* __restrict__ agg,
    const float* __restrict__ norm, const float* __restrict__ W,
    float* __restrict__ out, int N) {
  __shared__ float w[C][C];
  int tid = threadIdx.x;
  // cooperative load of W (4096 floats, 16 per thread), coalesced
  for (int i = tid; i < C * C; i += 256) {
    w[i >> 6][i & 63] = W[i];
  }
  __syncthreads();

  int lane = tid & 63;
  int wave = tid >> 6;  // 0..3
  int node0 = blockIdx.x * NODES_PER_BLOCK;
  int node_end = node0 + NODES_PER_BLOCK;
  if (node_end > N) node_end = N;

  for (int n = node0 + wave; n < node_end; n += 4) {
    long long base = (long long)n * C;
    float h = norm[n] * (x[base + lane] + agg[base + lane]);
    float acc = 0.0f;
#pragma unroll
    for (int k = 0; k < C; k++) {
      float hk = __shfl(h, k, 64);
      acc = fmaf(hk, w[k][lane], acc);
    }
    out[base + lane] = acc;
  }
}

extern "C" void kernel_launch(void* const* d_in, const int* in_sizes, int n_in,
                              void* d_out, int out_size, void* d_ws, size_t ws_size,
                              hipStream_t stream) {
  const float* x       = (const float*)d_in[0];
  const int*   sources = (const int*)d_in[1];
  const int*   targets = (const int*)d_in[2];
  const float* norm    = (const float*)d_in[3];
  const float* weight  = (const float*)d_in[4];
  float* out = (float*)d_out;

  int N = in_sizes[0] / C;   // 100000
  int E = in_sizes[1];       // 4000000

  float* agg = (float*)d_ws;  // N*C fp32 accumulator = 25.6 MB

  // zero the segment-sum accumulator (ws is re-poisoned to 0xAA every call)
  hipMemsetAsync(agg, 0, (size_t)N * C * sizeof(float), stream);

  // scatter: E*64 lanes, 256/block
  long long total = (long long)E * C;
  int blocks = (int)((total + 255) / 256);
  scatter_kernel<<<blocks, 256, 0, stream>>>(x, sources, targets, agg, E);

  // scale + matmul
  int blocks2 = (N + NODES_PER_BLOCK - 1) / NODES_PER_BLOCK;
  matmul_kernel<<<blocks2, 256, 0, stream>>>(x, agg, norm, weight, out, N);
}

// Round 2
// 1004.115 us; speedup vs baseline: 1.0281x; 1.0281x over previous
//
#include <hip/hip_runtime.h>

// Conv: out = (norm * (x + segment_sum(x[sources], targets))) @ W
// N = 100000, E = 4000000, C = 64, fp32.
// Strategy: build CSR by target on device (hist + scan + fill), then a fused
// gather/aggregate/scale/matmul kernel with ZERO fp32 atomics.

constexpr int C = 64;

// --- 1. histogram of targets -------------------------------------------------
__global__ __launch_bounds__(256) void hist_kernel(
    const int* __restrict__ tgt, int* __restrict__ counts, int E) {
  int e = blockIdx.x * 256 + threadIdx.x;
  if (e < E) atomicAdd(&counts[tgt[e]], 1);
}

// --- 2. exclusive scan (single block, 1024 threads) -------------------------
__global__ __launch_bounds__(1024) void scan_kernel(
    const int* __restrict__ counts, int* __restrict__ offsets,
    int* __restrict__ cursor, int N) {
  __shared__ int partials[1024];
  int tid = threadIdx.x;
  int chunk = (N + 1023) / 1024;
  int lo = tid * chunk;
  int hi = lo + chunk; if (hi > N) hi = N;
  if (lo > N) lo = N;
  int s = 0;
  for (int i = lo; i < hi; i++) s += counts[i];
  partials[tid] = s;
  __syncthreads();
  // Hillis-Steele inclusive scan over 1024 partials
  for (int off = 1; off < 1024; off <<= 1) {
    int v = partials[tid];
    int add = (tid >= off) ? partials[tid - off] : 0;
    __syncthreads();
    partials[tid] = v + add;
    __syncthreads();
  }
  int run = partials[tid] - s;  // exclusive prefix for this thread's chunk
  for (int i = lo; i < hi; i++) {
    offsets[i] = run;
    cursor[i] = run;
    run += counts[i];
  }
  if (tid == 1023) offsets[N] = partials[1023];
}

// --- 3. CSR fill -------------------------------------------------------------
__global__ __launch_bounds__(256) void fill_kernel(
    const int* __restrict__ src, const int* __restrict__ tgt,
    int* __restrict__ cursor, int* __restrict__ csr_src, int E) {
  int e = blockIdx.x * 256 + threadIdx.x;
  if (e < E) {
    int p = atomicAdd(&cursor[tgt[e]], 1);
    csr_src[p] = src[e];
  }
}

// --- 4. fused gather + aggregate + scale + matmul ---------------------------
// One wave per node (grid-stride). Lane = channel/output column.
// Edge indices: 64 loaded coalesced, then __shfl-broadcast one at a time.
// x[src] row reads are 256B coalesced per wave, served from L2/L3 (x = 25.6MB).
__global__ __launch_bounds__(256) void fused_kernel(
    const float* __restrict__ x, const int* __restrict__ offsets,
    const int* __restrict__ csr_src, const float* __restrict__ norm,
    const float* __restrict__ W, float* __restrict__ out, int N) {
  __shared__ float w[C][C];
  int tid = threadIdx.x;
  for (int i = tid; i < C * C; i += 256) w[i >> 6][i & 63] = W[i];
  __syncthreads();

  int lane = tid & 63;
  int wave = tid >> 6;
  int waves_total = gridDim.x * 4;

  for (int n = blockIdx.x * 4 + wave; n < N; n += waves_total) {
    int base_n = n * C;
    float acc = x[base_n + lane];  // self term
    int beg = offsets[n], end = offsets[n + 1];

    for (int base = beg; base < end; base += 64) {
      int rem = end - base;
      int cnt = rem < 64 ? rem : 64;
      int idx = (lane < rem) ? csr_src[base + lane] : 0;
      int j = 0;
      // 4-wide batches: 4 independent loads in flight per wave
      for (; j + 4 <= cnt; j += 4) {
        int s0 = __shfl(idx, j, 64);
        int s1 = __shfl(idx, j + 1, 64);
        int s2 = __shfl(idx, j + 2, 64);
        int s3 = __shfl(idx, j + 3, 64);
        float v0 = x[s0 * C + lane];
        float v1 = x[s1 * C + lane];
        float v2 = x[s2 * C + lane];
        float v3 = x[s3 * C + lane];
        acc += (v0 + v1) + (v2 + v3);
      }
      for (; j < cnt; j++) {
        int s0 = __shfl(idx, j, 64);
        acc += x[s0 * C + lane];
      }
    }

    float h = norm[n] * acc;
    float o = 0.0f;
#pragma unroll
    for (int k = 0; k < C; k++) {
      o = fmaf(__shfl(h, k, 64), w[k][lane], o);
    }
    out[base_n + lane] = o;
  }
}

extern "C" void kernel_launch(void* const* d_in, const int* in_sizes, int n_in,
                              void* d_out, int out_size, void* d_ws, size_t ws_size,
                              hipStream_t stream) {
  const float* x       = (const float*)d_in[0];
  const int*   sources = (const int*)d_in[1];
  const int*   targets = (const int*)d_in[2];
  const float* norm    = (const float*)d_in[3];
  const float* weight  = (const float*)d_in[4];
  float* out = (float*)d_out;

  int N = in_sizes[0] / C;   // 100000
  int E = in_sizes[1];       // 4000000

  // workspace layout (all int): offsets[N+1] | cursor[N] | counts[N] | csr_src[E]
  int* offsets = (int*)d_ws;
  int* cursor  = offsets + (N + 1);
  int* counts  = cursor + N;
  int* csr_src = counts + N;

  hipMemsetAsync(counts, 0, (size_t)N * sizeof(int), stream);

  int eblocks = (E + 255) / 256;
  hist_kernel<<<eblocks, 256, 0, stream>>>(targets, counts, E);
  scan_kernel<<<1, 1024, 0, stream>>>(counts, offsets, cursor, N);
  fill_kernel<<<eblocks, 256, 0, stream>>>(sources, targets, cursor, csr_src, E);

  fused_kernel<<<2048, 256, 0, stream>>>(x, offsets, csr_src, norm, weight, out, N);
}